// Round 2
// baseline (731.096 us; speedup 1.0000x reference)
//
#include <hip/hip_runtime.h>
#include <cmath>
#include <cstddef>

namespace {

constexpr int kB   = 4096;
constexpr int kT   = 1024;
constexpr int kI   = 8;
constexpr int kH   = 12;
constexpr int kA   = 4;
constexpr int kTC  = 32;              // timesteps per LDS chunk
constexpr int kEPB = 16;              // batch elements per block (one per 16-lane group)
constexpr int kXST = kTC * kI + 4;    // 260 floats: 16B-aligned rows, breaks bank alias

__device__ __forceinline__ float sigmoid_acc(float v) {
    return 1.0f / (1.0f + expf(-v));   // precise ocml exp + IEEE div
}
__device__ __forceinline__ float tanh_acc(float v) {
    return tanhf(v);                   // precise ocml tanh
}

__global__ __launch_bounds__(256, 1)
void lstm_fused_kernel(const float* __restrict__ x,
                       const float* __restrict__ W_ih,
                       const float* __restrict__ W_hh,
                       const float* __restrict__ b_ih,
                       const float* __restrict__ b_hh,
                       const float* __restrict__ W_fc,
                       const float* __restrict__ b_fc,
                       float* __restrict__ out) {
    __shared__ float xs[2][kEPB * kXST];   // staged x, double-buffered
    __shared__ float hsm[kEPB * 16];       // h broadcast buffer, per-group

    const int tid = threadIdx.x;
    const int e16 = tid >> 4;   // group (= batch element) within block
    const int ln  = tid & 15;   // lane within group
    const int wv  = tid >> 6;   // wave id
    const int l64 = tid & 63;   // lane within wave
    const int b   = blockIdx.x * kEPB + e16;

    // ---- weights to registers (one-time) ----
    const int j = (ln < kH) ? ln : (kH - 1);   // clamped hidden index
    float wih[4][8], whh[4][12], bias[4];
#pragma unroll
    for (int g = 0; g < 4; ++g) {              // PyTorch gate order i,f,g,o
        const int r = g * kH + j;
        const float4 a0 = *(const float4*)(W_ih + r * 8);
        const float4 a1 = *(const float4*)(W_ih + r * 8 + 4);
        wih[g][0] = a0.x; wih[g][1] = a0.y; wih[g][2] = a0.z; wih[g][3] = a0.w;
        wih[g][4] = a1.x; wih[g][5] = a1.y; wih[g][6] = a1.z; wih[g][7] = a1.w;
        const float4 c0 = *(const float4*)(W_hh + r * 12);
        const float4 c1 = *(const float4*)(W_hh + r * 12 + 4);
        const float4 c2 = *(const float4*)(W_hh + r * 12 + 8);
        whh[g][0] = c0.x; whh[g][1] = c0.y; whh[g][2]  = c0.z; whh[g][3]  = c0.w;
        whh[g][4] = c1.x; whh[g][5] = c1.y; whh[g][6]  = c1.z; whh[g][7]  = c1.w;
        whh[g][8] = c2.x; whh[g][9] = c2.y; whh[g][10] = c2.z; whh[g][11] = c2.w;
        bias[g] = b_ih[r] + b_hh[r];
    }
    const int a = (ln >= kH) ? (ln - kH) : 0;  // FC output index for lanes 12..15
    float wfc[12];
    {
        const float4 f0 = *(const float4*)(W_fc + a * 12);
        const float4 f1 = *(const float4*)(W_fc + a * 12 + 4);
        const float4 f2 = *(const float4*)(W_fc + a * 12 + 8);
        wfc[0] = f0.x; wfc[1] = f0.y; wfc[2]  = f0.z; wfc[3]  = f0.w;
        wfc[4] = f1.x; wfc[5] = f1.y; wfc[6]  = f1.z; wfc[7]  = f1.w;
        wfc[8] = f2.x; wfc[9] = f2.y; wfc[10] = f2.z; wfc[11] = f2.w;
    }
    const float bfc = b_fc[a];

    // ---- x staging addressing ----
    const int stt = l64 >> 1;          // staged timestep within chunk
    const int sio = (l64 & 1) << 2;    // staged input float offset (0 or 4)
    const int bw0 = blockIdx.x * kEPB + (wv << 2);
    const float* xb0 = x + ((size_t)bw0 * kT + stt) * kI + sio;
    const int wloc = (wv << 2) * kXST + stt * kI + sio;

    float4 rv0, rv1, rv2, rv3;
    {   // prologue: stage chunk 0 into buffer 0
        const float* p = xb0;
        rv0 = *(const float4*)(p);
        rv1 = *(const float4*)(p + kT * kI);
        rv2 = *(const float4*)(p + 2 * kT * kI);
        rv3 = *(const float4*)(p + 3 * kT * kI);
        float* d = &xs[0][wloc];
        *(float4*)(d)            = rv0;
        *(float4*)(d + kXST)     = rv1;
        *(float4*)(d + 2 * kXST) = rv2;
        *(float4*)(d + 3 * kXST) = rv3;
    }
    __syncthreads();   // staged chunk 0 visible

    float h = 0.0f, c = 0.0f;
    float hall[12];
#pragma unroll
    for (int k = 0; k < 12; ++k) hall[k] = 0.0f;

    int buf = 0;
#pragma unroll 1
    for (int ch = 0; ch < kT / kTC; ++ch) {
        if (ch + 1 < kT / kTC) {   // issue next chunk's global loads early
            const float* p = xb0 + (size_t)(ch + 1) * (kTC * kI);
            rv0 = *(const float4*)(p);
            rv1 = *(const float4*)(p + kT * kI);
            rv2 = *(const float4*)(p + 2 * kT * kI);
            rv3 = *(const float4*)(p + 3 * kT * kI);
        }
#pragma unroll 1
        for (int tt = 0; tt < kTC; ++tt) {
            const int t = ch * kTC + tt;
            if (ln < kH) {
                const float* xp = &xs[buf][e16 * kXST + tt * kI];
                const float4 xa  = *(const float4*)xp;
                const float4 xbv = *(const float4*)(xp + 4);
                const float xv[8] = {xa.x, xa.y, xa.z, xa.w, xbv.x, xbv.y, xbv.z, xbv.w};
                float gt[4];
#pragma unroll
                for (int g = 0; g < 4; ++g) {
                    float s = bias[g];
#pragma unroll
                    for (int i = 0; i < 8; ++i)  s = fmaf(wih[g][i], xv[i],   s);
#pragma unroll
                    for (int k = 0; k < 12; ++k) s = fmaf(whh[g][k], hall[k], s);
                    gt[g] = s;
                }
                const float iv = sigmoid_acc(gt[0]);
                const float fv = sigmoid_acc(gt[1]);
                const float gv = tanh_acc(gt[2]);
                const float ov = sigmoid_acc(gt[3]);
                c = fmaf(fv, c, iv * gv);
                h = ov * tanh_acc(c);
                hsm[(e16 << 4) + ln] = h;      // publish h_t to the group
            }
            __syncthreads();   // h_t visible to whole block (covers RAW)
            const float4 h0 = *(const float4*)&hsm[(e16 << 4) + 0];
            const float4 h1 = *(const float4*)&hsm[(e16 << 4) + 4];
            const float4 h2 = *(const float4*)&hsm[(e16 << 4) + 8];
            hall[0] = h0.x; hall[1] = h0.y; hall[2]  = h0.z; hall[3]  = h0.w;
            hall[4] = h1.x; hall[5] = h1.y; hall[6]  = h1.z; hall[7]  = h1.w;
            hall[8] = h2.x; hall[9] = h2.y; hall[10] = h2.z; hall[11] = h2.w;
            __syncthreads();   // reads done before next iteration's write (WAR)
            if (ln >= kH) {                    // dedicated FC lanes
                float s = bfc;
#pragma unroll
                for (int k = 0; k < 12; ++k) s = fmaf(wfc[k], hall[k], s);
                out[((size_t)b * kT + t) * kA + (ln - kH)] = s;
            }
        }
        if (ch + 1 < kT / kTC) {   // late LDS write of the prefetched chunk
            float* d = &xs[buf ^ 1][wloc];
            *(float4*)(d)            = rv0;
            *(float4*)(d + kXST)     = rv1;
            *(float4*)(d + 2 * kXST) = rv2;
            *(float4*)(d + 3 * kXST) = rv3;
        }
        __syncthreads();   // staged chunk visible before next chunk's reads
        buf ^= 1;
    }

    if (ln < kH) {   // hn, cn (shapes [1,B,12] each), concatenated after out
        float* hn = out + (size_t)kB * kT * kA;
        hn[b * kH + ln] = h;
        hn[(size_t)kB * kH + b * kH + ln] = c;
    }
}

}  // namespace

extern "C" void kernel_launch(void* const* d_in, const int* in_sizes, int n_in,
                              void* d_out, int out_size, void* d_ws, size_t ws_size,
                              hipStream_t stream) {
    (void)in_sizes; (void)n_in; (void)d_ws; (void)ws_size; (void)out_size;
    const float* x    = (const float*)d_in[0];
    const float* W_ih = (const float*)d_in[1];
    const float* W_hh = (const float*)d_in[2];
    const float* b_ih = (const float*)d_in[3];
    const float* b_hh = (const float*)d_in[4];
    const float* W_fc = (const float*)d_in[5];
    const float* b_fc = (const float*)d_in[6];
    float* out = (float*)d_out;
    hipLaunchKernelGGL(lstm_fused_kernel, dim3(kB / kEPB), dim3(256), 0, stream,
                       x, W_ih, W_hh, b_ih, b_hh, W_fc, b_fc, out);
}

// Round 3
// 385.167 us; speedup vs baseline: 1.8981x; 1.8981x over previous
//
#include <hip/hip_runtime.h>
#include <cstddef>

namespace {

constexpr int kB   = 4096;
constexpr int kT   = 1024;
constexpr int kI   = 8;
constexpr int kH   = 12;
constexpr int kA   = 4;
constexpr int kTC  = 32;              // timesteps per LDS chunk
constexpr int kEPB = 16;              // batch elements per block (one per 16-lane group)
constexpr int kXST = kTC * kI + 4;    // 260 floats: 16B-aligned rows, breaks bank alias

__device__ __forceinline__ float fast_sigmoid(float v) {
    float e = __builtin_amdgcn_exp2f(-1.442695041f * v);
    return __builtin_amdgcn_rcpf(1.0f + e);   // saturates correctly at +/-inf
}
__device__ __forceinline__ float fast_tanh(float v) {
    float e = __builtin_amdgcn_exp2f(-2.885390082f * v);
    return fmaf(2.0f, __builtin_amdgcn_rcpf(1.0f + e), -1.0f);
}

__global__ __launch_bounds__(256, 1)
void lstm_fused_kernel(const float* __restrict__ x,
                       const float* __restrict__ W_ih,
                       const float* __restrict__ W_hh,
                       const float* __restrict__ b_ih,
                       const float* __restrict__ b_hh,
                       const float* __restrict__ W_fc,
                       const float* __restrict__ b_fc,
                       float* __restrict__ out) {
    __shared__ float xs[2][kEPB * kXST];   // staged x, double-buffered, wave-private regions

    const int tid = threadIdx.x;
    const int e16 = tid >> 4;   // group (= batch element) within block
    const int ln  = tid & 15;   // lane within group
    const int wv  = tid >> 6;   // wave id
    const int l64 = tid & 63;   // lane within wave
    const int b   = blockIdx.x * kEPB + e16;

    // ---- weights to registers (one-time); lanes 12..15 clone j=11 (harmless) ----
    const int j = (ln < kH) ? ln : (kH - 1);
    float wih[4][8], whh[4][12], bias[4];
#pragma unroll
    for (int g = 0; g < 4; ++g) {              // PyTorch gate order i,f,g,o
        const int r = g * kH + j;
        const float4 a0 = *(const float4*)(W_ih + r * 8);
        const float4 a1 = *(const float4*)(W_ih + r * 8 + 4);
        wih[g][0] = a0.x; wih[g][1] = a0.y; wih[g][2] = a0.z; wih[g][3] = a0.w;
        wih[g][4] = a1.x; wih[g][5] = a1.y; wih[g][6] = a1.z; wih[g][7] = a1.w;
        const float4 c0 = *(const float4*)(W_hh + r * 12);
        const float4 c1 = *(const float4*)(W_hh + r * 12 + 4);
        const float4 c2 = *(const float4*)(W_hh + r * 12 + 8);
        whh[g][0] = c0.x; whh[g][1] = c0.y; whh[g][2]  = c0.z; whh[g][3]  = c0.w;
        whh[g][4] = c1.x; whh[g][5] = c1.y; whh[g][6]  = c1.z; whh[g][7]  = c1.w;
        whh[g][8] = c2.x; whh[g][9] = c2.y; whh[g][10] = c2.z; whh[g][11] = c2.w;
        bias[g] = b_ih[r] + b_hh[r];
    }
    const int a = (ln >= kH) ? (ln - kH) : 0;  // FC output index for lanes 12..15
    float wfc[12];
    {
        const float4 f0 = *(const float4*)(W_fc + a * 12);
        const float4 f1 = *(const float4*)(W_fc + a * 12 + 4);
        const float4 f2 = *(const float4*)(W_fc + a * 12 + 8);
        wfc[0] = f0.x; wfc[1] = f0.y; wfc[2]  = f0.z; wfc[3]  = f0.w;
        wfc[4] = f1.x; wfc[5] = f1.y; wfc[6]  = f1.z; wfc[7]  = f1.w;
        wfc[8] = f2.x; wfc[9] = f2.y; wfc[10] = f2.z; wfc[11] = f2.w;
    }
    const float bfc = b_fc[a];

    // bpermute base: lane index of this 16-lane group's lane 0, in bytes
    const int bpbase = (l64 & ~15) << 2;

    // ---- x staging addressing (wave-private; fence-only ordering) ----
    const int stt = l64 >> 1;          // staged timestep within chunk
    const int sio = (l64 & 1) << 2;    // staged input float offset (0 or 4)
    const int bw0 = blockIdx.x * kEPB + (wv << 2);
    const float* xb0 = x + ((size_t)bw0 * kT + stt) * kI + sio;
    const int wloc = (wv << 2) * kXST + stt * kI + sio;

    float4 rv0, rv1, rv2, rv3;
    {   // prologue: stage chunk 0 into buffer 0
        const float* p = xb0;
        rv0 = *(const float4*)(p);
        rv1 = *(const float4*)(p + kT * kI);
        rv2 = *(const float4*)(p + 2 * kT * kI);
        rv3 = *(const float4*)(p + 3 * kT * kI);
        float* d = &xs[0][wloc];
        *(float4*)(d)            = rv0;
        *(float4*)(d + kXST)     = rv1;
        *(float4*)(d + 2 * kXST) = rv2;
        *(float4*)(d + 3 * kXST) = rv3;
    }
    asm volatile("s_waitcnt lgkmcnt(0)" ::: "memory");  // staged chunk 0 visible (wave-private)
    __builtin_amdgcn_sched_barrier(0);

    float h = 0.0f, c = 0.0f;
    float hall[12];
#pragma unroll
    for (int k = 0; k < 12; ++k) hall[k] = 0.0f;

    int buf = 0;
#pragma unroll 1
    for (int ch = 0; ch < kT / kTC; ++ch) {
        if (ch + 1 < kT / kTC) {   // issue next chunk's global loads early
            const float* p = xb0 + (size_t)(ch + 1) * (kTC * kI);
            rv0 = *(const float4*)(p);
            rv1 = *(const float4*)(p + kT * kI);
            rv2 = *(const float4*)(p + 2 * kT * kI);
            rv3 = *(const float4*)(p + 3 * kT * kI);
        }
#pragma unroll 2
        for (int tt = 0; tt < kTC; ++tt) {
            const int t = ch * kTC + tt;
            // x broadcast read (same addr within group -> LDS broadcast)
            const float* xp = &xs[buf][e16 * kXST + tt * kI];
            const float4 xa  = *(const float4*)xp;
            const float4 xbv = *(const float4*)(xp + 4);
            const float xv[8] = {xa.x, xa.y, xa.z, xa.w, xbv.x, xbv.y, xbv.z, xbv.w};
            float gt[4];
#pragma unroll
            for (int g = 0; g < 4; ++g) {
                float s = bias[g];
#pragma unroll
                for (int k = 0; k < 12; ++k) s = fmaf(whh[g][k], hall[k], s);  // h-part first
#pragma unroll
                for (int i = 0; i < 8; ++i)  s = fmaf(wih[g][i], xv[i],   s);  // x-part last
                gt[g] = s;
            }
            const float iv = fast_sigmoid(gt[0]);
            const float fv = fast_sigmoid(gt[1]);
            const float gv = fast_tanh(gt[2]);
            const float ov = fast_sigmoid(gt[3]);
            c = fmaf(fv, c, iv * gv);
            h = ov * fast_tanh(c);
            // broadcast h_t via register permute (no LDS memory, no ordering hazard)
            const int hb = __float_as_int(h);
#pragma unroll
            for (int k = 0; k < 12; ++k)
                hall[k] = __int_as_float(__builtin_amdgcn_ds_bpermute(bpbase + (k << 2), hb));
            // FC from freshly broadcast h_t (covers bpermute latency)
            float s = bfc;
#pragma unroll
            for (int k = 0; k < 12; ++k) s = fmaf(wfc[k], hall[k], s);
            if (ln >= kH) out[((size_t)b * kT + t) * kA + a] = s;
        }
        if (ch + 1 < kT / kTC) {   // late LDS write of the prefetched chunk
            float* d = &xs[buf ^ 1][wloc];
            *(float4*)(d)            = rv0;
            *(float4*)(d + kXST)     = rv1;
            *(float4*)(d + 2 * kXST) = rv2;
            *(float4*)(d + 3 * kXST) = rv3;
            asm volatile("s_waitcnt lgkmcnt(0)" ::: "memory");  // wave-private visibility
            __builtin_amdgcn_sched_barrier(0);
        }
        buf ^= 1;
    }

    if (ln < kH) {   // hn, cn (shapes [1,B,12] each), concatenated after out
        float* hn = out + (size_t)kB * kT * kA;
        hn[b * kH + ln] = h;
        hn[(size_t)kB * kH + b * kH + ln] = c;
    }
}

}  // namespace

extern "C" void kernel_launch(void* const* d_in, const int* in_sizes, int n_in,
                              void* d_out, int out_size, void* d_ws, size_t ws_size,
                              hipStream_t stream) {
    (void)in_sizes; (void)n_in; (void)d_ws; (void)ws_size; (void)out_size;
    const float* x    = (const float*)d_in[0];
    const float* W_ih = (const float*)d_in[1];
    const float* W_hh = (const float*)d_in[2];
    const float* b_ih = (const float*)d_in[3];
    const float* b_hh = (const float*)d_in[4];
    const float* W_fc = (const float*)d_in[5];
    const float* b_fc = (const float*)d_in[6];
    float* out = (float*)d_out;
    hipLaunchKernelGGL(lstm_fused_kernel, dim3(kB / kEPB), dim3(256), 0, stream,
                       x, W_ih, W_hh, b_ih, b_hh, W_fc, b_fc, out);
}